// Round 3
// baseline (441.592 us; speedup 1.0000x reference)
//
#include <hip/hip_runtime.h>
#include <math.h>

#define BATCH 4
#define TSEQ  2048
#define CEMB  1024
#define NHEAD 16
#define HD    64
#define MROWS (BATCH * TSEQ)   // 8192

typedef _Float16 half8 __attribute__((ext_vector_type(8)));
typedef _Float16 half4 __attribute__((ext_vector_type(4)));
typedef float    floatx4 __attribute__((ext_vector_type(4)));

#define GLOBAL_AS __attribute__((address_space(1)))
#define LDS_AS    __attribute__((address_space(3)))

__device__ __forceinline__ void lds_dma16(const _Float16* g, _Float16* l) {
    __builtin_amdgcn_global_load_lds((const GLOBAL_AS unsigned int*)g,
                                     (LDS_AS unsigned int*)l, 16, 0, 0);
}

// ---------------------------------------------------------------------------
// Kernel 0: fp32 -> fp16 convert prepass (float4 -> half4)
// ---------------------------------------------------------------------------
__global__ __launch_bounds__(256)
void cvt_fp16(const float* __restrict__ x, const float* __restrict__ wa,
              const float* __restrict__ wp, _Float16* __restrict__ x16,
              _Float16* __restrict__ wa16, _Float16* __restrict__ wp16)
{
    const int n1 = (BATCH * TSEQ * CEMB) / 4;
    const int n2 = (3 * CEMB * CEMB) / 4;
    int i = blockIdx.x * 256 + threadIdx.x;
    const float* src; _Float16* dst; int j;
    if (i < n1)            { src = x;  dst = x16;  j = i; }
    else if (i < n1 + n2)  { src = wa; dst = wa16; j = i - n1; }
    else                   { src = wp; dst = wp16; j = i - n1 - n2; }
    float4 v = ((const float4*)src)[j];
    half4 h = { (_Float16)v.x, (_Float16)v.y, (_Float16)v.z, (_Float16)v.w };
    ((half4*)dst)[j] = h;
}

// ---------------------------------------------------------------------------
// GEMM staging: 128x32 fp16 tile via global_load_lds width=16, XOR-swizzled
// 16B chunks (pc ^ ((row>>1)&3)) so fragment b128 reads are conflict-light.
// ---------------------------------------------------------------------------
__device__ __forceinline__ void stage_tile(const _Float16* __restrict__ gbase,
                                           _Float16* __restrict__ lds,
                                           int row0, int kk, int tid)
{
#pragma unroll
    for (int p = 0; p < 2; ++p) {
        int ci  = p * 256 + tid;
        int row = ci >> 2, pc = ci & 3;
        int gc  = pc ^ ((row >> 1) & 3);
        lds_dma16(gbase + (size_t)(row0 + row) * CEMB + kk + gc * 8, lds + ci * 8);
    }
}

// ---------------------------------------------------------------------------
// Kernel 1: qkv = x16 @ Wa16^T; epilogue scatters q (PRE-SCALED x8), k, V^T.
// ---------------------------------------------------------------------------
__global__ __launch_bounds__(256)
void qkv_gemm(const _Float16* __restrict__ A, const _Float16* __restrict__ B,
              _Float16* __restrict__ q16, _Float16* __restrict__ k16,
              _Float16* __restrict__ v16)
{
    __shared__ __align__(16) _Float16 As[128 * 32];
    __shared__ __align__(16) _Float16 Bs[128 * 32];
    const int tid = threadIdx.x, lane = tid & 63, wave = tid >> 6;
    const int wm = wave & 1, wn = wave >> 1;
    const int m0 = blockIdx.y * 128, n0 = blockIdx.x * 128;
    const int l15 = lane & 15, quad = lane >> 4;
    const int sw = (l15 >> 1) & 3;

    floatx4 acc[4][4];
#pragma unroll
    for (int i = 0; i < 4; ++i)
#pragma unroll
        for (int j = 0; j < 4; ++j) acc[i][j] = (floatx4){0.f, 0.f, 0.f, 0.f};

    for (int kk = 0; kk < CEMB; kk += 32) {
        __syncthreads();
        stage_tile(A, As, m0, kk, tid);
        stage_tile(B, Bs, n0, kk, tid);
        __syncthreads();
        half8 af[4], bf[4];
#pragma unroll
        for (int mt = 0; mt < 4; ++mt)
            af[mt] = *(const half8*)(As + (wm * 64 + mt * 16 + l15) * 32 + ((quad ^ sw) << 3));
#pragma unroll
        for (int nt = 0; nt < 4; ++nt)
            bf[nt] = *(const half8*)(Bs + (wn * 64 + nt * 16 + l15) * 32 + ((quad ^ sw) << 3));
#pragma unroll
        for (int mt = 0; mt < 4; ++mt)
#pragma unroll
            for (int nt = 0; nt < 4; ++nt)
                acc[mt][nt] = __builtin_amdgcn_mfma_f32_16x16x32_f16(af[mt], bf[nt], acc[mt][nt], 0, 0, 0);
    }

    const int rbase = quad << 2;
#pragma unroll
    for (int mt = 0; mt < 4; ++mt) {
#pragma unroll
        for (int nt = 0; nt < 4; ++nt) {
            int gn = n0 + wn * 64 + nt * 16 + l15;
#pragma unroll
            for (int r = 0; r < 4; ++r) {
                int gm = m0 + wm * 64 + mt * 16 + rbase + r;
                int b = gm >> 11, t = gm & (TSEQ - 1);
                if (gn < CEMB) {
                    int h = gn >> 6, d = gn & 63;
                    // fold logit scale sqrt(hd)=8 into q (exact pow2)
                    q16[(((size_t)(b * NHEAD + h)) * TSEQ + t) * HD + d] =
                        (_Float16)(acc[mt][nt][r] * 8.0f);
                } else if (gn < 2 * CEMB) {
                    int c2 = gn - CEMB;
                    int h = c2 >> 6, d = c2 & 63;
                    k16[(((size_t)(b * NHEAD + h)) * TSEQ + t) * HD + d] =
                        (_Float16)acc[mt][nt][r];
                } else {
                    int c2 = gn - 2 * CEMB;
                    int h = c2 >> 6, d = c2 & 63;
                    v16[(((size_t)(b * NHEAD + h)) * HD + d) * TSEQ + t] =
                        (_Float16)acc[mt][nt][r];   // V^T
                }
            }
        }
    }
}

// ---------------------------------------------------------------------------
// Kernel 2: flash attention. S^T = K·Q^T (swapped-operand 16x16x32 MFMA) so
// softmaxed P sits in registers ALREADY in B-fragment layout for
// mfma_f32_16x16x16f16; PV = V^T·P^T with zero LDS transpose. Paired q-tiles
// for load balance; double-buffered K/V staging (one barrier per k-tile).
// ---------------------------------------------------------------------------
__device__ __forceinline__ void attn_tile(
    const half8& qf0, const half8& qf1,
    float& m_i, float& l_i, floatx4 (&o)[4],
    const _Float16* __restrict__ Ks, const _Float16* __restrict__ Vs,
    bool domask, int l15, int quad, int relq)
{
    floatx4 s[4];
#pragma unroll
    for (int nt = 0; nt < 4; ++nt) {
        half8 kf0 = *(const half8*)(Ks + (nt * 16 + l15) * 72 + quad * 8);
        half8 kf1 = *(const half8*)(Ks + (nt * 16 + l15) * 72 + 32 + quad * 8);
        floatx4 z = (floatx4){0.f, 0.f, 0.f, 0.f};
        z = __builtin_amdgcn_mfma_f32_16x16x32_f16(kf0, qf0, z, 0, 0, 0);  // A=K
        z = __builtin_amdgcn_mfma_f32_16x16x32_f16(kf1, qf1, z, 0, 0, 0);  // B=Q
        s[nt] = z;   // S^T[key = nt*16+quad*4+r][q = l15]  (already x8 via q)
    }
    if (domask) {
#pragma unroll
        for (int nt = 0; nt < 4; ++nt)
#pragma unroll
            for (int r = 0; r < 4; ++r)
                if (nt * 16 + quad * 4 + r > relq) s[nt][r] = -INFINITY;
    }
    float mx = m_i;
#pragma unroll
    for (int nt = 0; nt < 4; ++nt)
        mx = fmaxf(mx, fmaxf(fmaxf(s[nt][0], s[nt][1]), fmaxf(s[nt][2], s[nt][3])));
    mx = fmaxf(mx, __shfl_xor(mx, 16, 64));
    mx = fmaxf(mx, __shfl_xor(mx, 32, 64));
    float alpha = __expf(m_i - mx);
    m_i = mx;
    float rs = 0.f;
    half4 p[4];
#pragma unroll
    for (int nt = 0; nt < 4; ++nt) {
        float p0 = __expf(s[nt][0] - mx), p1 = __expf(s[nt][1] - mx);
        float p2 = __expf(s[nt][2] - mx), p3 = __expf(s[nt][3] - mx);
        rs += (p0 + p1) + (p2 + p3);
        p[nt] = (half4){ (_Float16)p0, (_Float16)p1, (_Float16)p2, (_Float16)p3 };
    }
    rs += __shfl_xor(rs, 16, 64);
    rs += __shfl_xor(rs, 32, 64);
    l_i = l_i * alpha + rs;
#pragma unroll
    for (int mt = 0; mt < 4; ++mt)
#pragma unroll
        for (int r = 0; r < 4; ++r) o[mt][r] *= alpha;
    // O^T += V^T · P^T : A = V^T fragment (half4, contiguous keys), B = p[nt]
#pragma unroll
    for (int mt = 0; mt < 4; ++mt)
#pragma unroll
        for (int nt = 0; nt < 4; ++nt) {
            half4 vf = *(const half4*)(Vs + (mt * 16 + l15) * 72 + nt * 16 + quad * 4);
            o[mt] = __builtin_amdgcn_mfma_f32_16x16x16f16(vf, p[nt], o[mt], 0, 0, 0);
        }
}

__global__ __launch_bounds__(256, 4)
void attn_fwd(const _Float16* __restrict__ q16, const _Float16* __restrict__ k16,
              const _Float16* __restrict__ v16, _Float16* __restrict__ o16)
{
    __shared__ __align__(16) _Float16 Ks[2][64 * 72];
    __shared__ __align__(16) _Float16 Vs[2][64 * 72];
    const int tid = threadIdx.x, lane = tid & 63, wave = tid >> 6;
    const int l15 = lane & 15, quad = lane >> 4;
    const int qtA = blockIdx.x;        // 0..15
    const int qtB = 31 - qtA;          // 31..16
    const int bh = blockIdx.y, b = bh >> 4, h = bh & 15;
    const int q0A = qtA * 64, q0B = qtB * 64;
    const _Float16* qp = q16 + (size_t)bh * TSEQ * HD;
    const _Float16* kp = k16 + (size_t)bh * TSEQ * HD;
    const _Float16* vp = v16 + (size_t)bh * HD * TSEQ;

    const int relq = wave * 16 + l15;          // q row within 64-tile (per lane)
    half8 qA0 = *(const half8*)(qp + (size_t)(q0A + relq) * HD + quad * 8);
    half8 qA1 = *(const half8*)(qp + (size_t)(q0A + relq) * HD + 32 + quad * 8);
    half8 qB0 = *(const half8*)(qp + (size_t)(q0B + relq) * HD + quad * 8);
    half8 qB1 = *(const half8*)(qp + (size_t)(q0B + relq) * HD + 32 + quad * 8);

    float mA = -INFINITY, lA = 0.f, mB = -INFINITY, lB = 0.f;
    floatx4 oA[4], oB[4];
#pragma unroll
    for (int mt = 0; mt < 4; ++mt) { oA[mt] = (floatx4){0.f,0.f,0.f,0.f}; oB[mt] = (floatx4){0.f,0.f,0.f,0.f}; }

    // staging indices: thread covers rows {tid>>3, 32+(tid>>3)}, chunk (tid&7)*8
    const int srow = tid >> 3, sch = (tid & 7) << 3;

    // prologue: stage tile 0 into buffer 0
    {
        half8 k0 = *(const half8*)(kp + (size_t)srow * HD + sch);
        half8 k1 = *(const half8*)(kp + (size_t)(32 + srow) * HD + sch);
        half8 v0 = *(const half8*)(vp + (size_t)srow * TSEQ + sch);
        half8 v1 = *(const half8*)(vp + (size_t)(32 + srow) * TSEQ + sch);
        *(half8*)(Ks[0] + srow * 72 + sch) = k0;
        *(half8*)(Ks[0] + (32 + srow) * 72 + sch) = k1;
        *(half8*)(Vs[0] + srow * 72 + sch) = v0;
        *(half8*)(Vs[0] + (32 + srow) * 72 + sch) = v1;
    }
    __syncthreads();

    for (int kt = 0; kt <= qtB; ++kt) {
        const int cur = kt & 1;
        half8 k0, k1, v0, v1;
        const bool more = (kt < qtB);
        if (more) {   // issue next tile's global loads before compute
            const int nt0 = (kt + 1) * 64;
            k0 = *(const half8*)(kp + (size_t)(nt0 + srow) * HD + sch);
            k1 = *(const half8*)(kp + (size_t)(nt0 + 32 + srow) * HD + sch);
            v0 = *(const half8*)(vp + (size_t)srow * TSEQ + nt0 + sch);
            v1 = *(const half8*)(vp + (size_t)(32 + srow) * TSEQ + nt0 + sch);
        }
        attn_tile(qB0, qB1, mB, lB, oB, Ks[cur], Vs[cur], (kt == qtB), l15, quad, relq);
        if (kt <= qtA)
            attn_tile(qA0, qA1, mA, lA, oA, Ks[cur], Vs[cur], (kt == qtA), l15, quad, relq);
        if (more) {
            _Float16* kd = Ks[1 - cur];
            _Float16* vd = Vs[1 - cur];
            *(half8*)(kd + srow * 72 + sch) = k0;
            *(half8*)(kd + (32 + srow) * 72 + sch) = k1;
            *(half8*)(vd + srow * 72 + sch) = v0;
            *(half8*)(vd + (32 + srow) * 72 + sch) = v1;
        }
        __syncthreads();
    }

    // epilogue: O^T lane holds O[q=l15(+wave*16)][d=mt*16+quad*4+r] -> half4 stores
    const float invA = 1.f / lA, invB = 1.f / lB;
    const size_t baseA = ((size_t)(b * TSEQ + q0A + relq)) * CEMB + h * HD + quad * 4;
    const size_t baseB = ((size_t)(b * TSEQ + q0B + relq)) * CEMB + h * HD + quad * 4;
#pragma unroll
    for (int mt = 0; mt < 4; ++mt) {
        half4 ha = { (_Float16)(oA[mt][0] * invA), (_Float16)(oA[mt][1] * invA),
                     (_Float16)(oA[mt][2] * invA), (_Float16)(oA[mt][3] * invA) };
        half4 hb = { (_Float16)(oB[mt][0] * invB), (_Float16)(oB[mt][1] * invB),
                     (_Float16)(oB[mt][2] * invB), (_Float16)(oB[mt][3] * invB) };
        *(half4*)(o16 + baseA + mt * 16) = ha;
        *(half4*)(o16 + baseB + mt * 16) = hb;
    }
}

// ---------------------------------------------------------------------------
// Kernel 3: y = attn16 @ Wp16^T + b_proj, fp32 out
// ---------------------------------------------------------------------------
__global__ __launch_bounds__(256)
void proj_gemm(const _Float16* __restrict__ A, const _Float16* __restrict__ B,
               const float* __restrict__ bias, float* __restrict__ out)
{
    __shared__ __align__(16) _Float16 As[128 * 32];
    __shared__ __align__(16) _Float16 Bs[128 * 32];
    const int tid = threadIdx.x, lane = tid & 63, wave = tid >> 6;
    const int wm = wave & 1, wn = wave >> 1;
    const int m0 = blockIdx.y * 128, n0 = blockIdx.x * 128;
    const int l15 = lane & 15, quad = lane >> 4;
    const int sw = (l15 >> 1) & 3;

    floatx4 acc[4][4];
#pragma unroll
    for (int i = 0; i < 4; ++i)
#pragma unroll
        for (int j = 0; j < 4; ++j) acc[i][j] = (floatx4){0.f, 0.f, 0.f, 0.f};

    for (int kk = 0; kk < CEMB; kk += 32) {
        __syncthreads();
        stage_tile(A, As, m0, kk, tid);
        stage_tile(B, Bs, n0, kk, tid);
        __syncthreads();
        half8 af[4], bf[4];
#pragma unroll
        for (int mt = 0; mt < 4; ++mt)
            af[mt] = *(const half8*)(As + (wm * 64 + mt * 16 + l15) * 32 + ((quad ^ sw) << 3));
#pragma unroll
        for (int nt = 0; nt < 4; ++nt)
            bf[nt] = *(const half8*)(Bs + (wn * 64 + nt * 16 + l15) * 32 + ((quad ^ sw) << 3));
#pragma unroll
        for (int mt = 0; mt < 4; ++mt)
#pragma unroll
            for (int nt = 0; nt < 4; ++nt)
                acc[mt][nt] = __builtin_amdgcn_mfma_f32_16x16x32_f16(af[mt], bf[nt], acc[mt][nt], 0, 0, 0);
    }

    const int rbase = quad << 2;
#pragma unroll
    for (int mt = 0; mt < 4; ++mt)
#pragma unroll
        for (int nt = 0; nt < 4; ++nt) {
            int gn = n0 + wn * 64 + nt * 16 + l15;
            float bb = bias[gn];
#pragma unroll
            for (int r = 0; r < 4; ++r) {
                int gm = m0 + wm * 64 + mt * 16 + rbase + r;
                out[(size_t)gm * CEMB + gn] = acc[mt][nt][r] + bb;
            }
        }
}

// ---------------------------------------------------------------------------
extern "C" void kernel_launch(void* const* d_in, const int* in_sizes, int n_in,
                              void* d_out, int out_size, void* d_ws, size_t ws_size,
                              hipStream_t stream) {
    const float* x     = (const float*)d_in[0];
    const float* Wattn = (const float*)d_in[1];
    const float* Wproj = (const float*)d_in[2];
    const float* bproj = (const float*)d_in[3];
    float* out = (float*)d_out;

    const size_t nx  = (size_t)BATCH * TSEQ * CEMB;
    const size_t nwa = (size_t)3 * CEMB * CEMB;
    const size_t nwp = (size_t)CEMB * CEMB;
    const size_t per = (size_t)BATCH * NHEAD * TSEQ * HD;

    _Float16* x16    = (_Float16*)d_ws;
    _Float16* wa16   = x16 + nx;
    _Float16* wp16   = wa16 + nwa;
    _Float16* q16    = wp16 + nwp;
    _Float16* k16    = q16 + per;
    _Float16* v16    = k16 + per;
    _Float16* attn16 = x16;   // alias: x16 fully consumed before attn writes

    const int nconv = (int)((nx + nwa + nwp) / 4);
    cvt_fp16<<<nconv / 256, 256, 0, stream>>>(x, Wattn, Wproj, x16, wa16, wp16);
    qkv_gemm<<<dim3(3 * CEMB / 128, MROWS / 128), 256, 0, stream>>>(x16, wa16, q16, k16, v16);
    attn_fwd<<<dim3(16, BATCH * NHEAD), 256, 0, stream>>>(q16, k16, v16, attn16);
    proj_gemm<<<dim3(CEMB / 128, MROWS / 128), 256, 0, stream>>>(attn16, wp16, bproj, out);
}

// Round 4
// 324.291 us; speedup vs baseline: 1.3617x; 1.3617x over previous
//
#include <hip/hip_runtime.h>
#include <math.h>

#define BATCH 4
#define TSEQ  2048
#define CEMB  1024
#define NHEAD 16
#define HD    64
#define MROWS (BATCH * TSEQ)   // 8192

typedef _Float16 half8 __attribute__((ext_vector_type(8)));
typedef _Float16 half4 __attribute__((ext_vector_type(4)));
typedef float    floatx4 __attribute__((ext_vector_type(4)));

#define GLOBAL_AS __attribute__((address_space(1)))
#define LDS_AS    __attribute__((address_space(3)))

// async global->LDS DMA, 16 B/lane; dest must be lane-contiguous per wave.
__device__ __forceinline__ void lds_dma16(const _Float16* g, _Float16* l) {
    __builtin_amdgcn_global_load_lds((const GLOBAL_AS unsigned int*)g,
                                     (LDS_AS unsigned int*)l, 16, 0, 0);
}

// ---------------------------------------------------------------------------
// Kernel 0: fp32 -> fp16 convert prepass (float4 -> half4)
// ---------------------------------------------------------------------------
__global__ __launch_bounds__(256)
void cvt_fp16(const float* __restrict__ x, const float* __restrict__ wa,
              const float* __restrict__ wp, _Float16* __restrict__ x16,
              _Float16* __restrict__ wa16, _Float16* __restrict__ wp16)
{
    const int n1 = (BATCH * TSEQ * CEMB) / 4;
    const int n2 = (3 * CEMB * CEMB) / 4;
    int i = blockIdx.x * 256 + threadIdx.x;
    const float* src; _Float16* dst; int j;
    if (i < n1)            { src = x;  dst = x16;  j = i; }
    else if (i < n1 + n2)  { src = wa; dst = wa16; j = i - n1; }
    else                   { src = wp; dst = wp16; j = i - n1 - n2; }
    float4 v = ((const float4*)src)[j];
    half4 h = { (_Float16)v.x, (_Float16)v.y, (_Float16)v.z, (_Float16)v.w };
    ((half4*)dst)[j] = h;
}

// ---------------------------------------------------------------------------
// GEMM staging: 128x32 fp16 tile, DMA, XOR swizzle pc = c ^ (row&3).
// Fragment reads (pc = quad ^ (row&3)) are conflict-free at wave64 minimum.
// ---------------------------------------------------------------------------
__device__ __forceinline__ void stage32(const _Float16* __restrict__ gbase,
                                        _Float16* __restrict__ lds,
                                        int row0, int kk, int tid)
{
#pragma unroll
    for (int p = 0; p < 2; ++p) {
        int ci  = p * 256 + tid;          // 512 chunks = 128 rows x 4
        int row = ci >> 2, pcc = ci & 3;
        int c   = pcc ^ (row & 3);
        lds_dma16(gbase + (size_t)(row0 + row) * CEMB + kk + c * 8, lds + ci * 8);
    }
}

__device__ __forceinline__ void gemm_frags(const _Float16* __restrict__ As,
                                           const _Float16* __restrict__ Bs,
                                           int wm, int wn, int l15, int quad,
                                           half8 (&af)[4], half8 (&bf)[4])
{
#pragma unroll
    for (int mt = 0; mt < 4; ++mt) {
        int row = wm * 64 + mt * 16 + l15;
        af[mt] = *(const half8*)(As + row * 32 + (quad ^ (row & 3)) * 8);
    }
#pragma unroll
    for (int nt = 0; nt < 4; ++nt) {
        int row = wn * 64 + nt * 16 + l15;
        bf[nt] = *(const half8*)(Bs + row * 32 + (quad ^ (row & 3)) * 8);
    }
}

// ---------------------------------------------------------------------------
// Kernel 1: qkv = x16 @ Wa16^T; epilogue scatters q (PRE-SCALED x8), k, V^T.
// Double-buffered DMA staging, one barrier per k-step.
// ---------------------------------------------------------------------------
__global__ __launch_bounds__(256)
void qkv_gemm(const _Float16* __restrict__ A, const _Float16* __restrict__ B,
              _Float16* __restrict__ q16, _Float16* __restrict__ k16,
              _Float16* __restrict__ v16)
{
    __shared__ __align__(16) _Float16 As[2][128 * 32];
    __shared__ __align__(16) _Float16 Bs[2][128 * 32];
    const int tid = threadIdx.x, lane = tid & 63, wave = tid >> 6;
    const int wm = wave & 1, wn = wave >> 1;
    const int m0 = blockIdx.y * 128, n0 = blockIdx.x * 128;
    const int l15 = lane & 15, quad = lane >> 4;

    floatx4 acc[4][4];
#pragma unroll
    for (int i = 0; i < 4; ++i)
#pragma unroll
        for (int j = 0; j < 4; ++j) acc[i][j] = (floatx4){0.f, 0.f, 0.f, 0.f};

    stage32(A, As[0], m0, 0, tid);
    stage32(B, Bs[0], n0, 0, tid);
    for (int kt = 0; kt < 32; ++kt) {
        const int cur = kt & 1;
        __syncthreads();                      // drains DMA(kt)
        if (kt < 31) {                        // prefetch kt+1, hides behind MFMA
            stage32(A, As[cur ^ 1], m0, (kt + 1) * 32, tid);
            stage32(B, Bs[cur ^ 1], n0, (kt + 1) * 32, tid);
        }
        half8 af[4], bf[4];
        gemm_frags(As[cur], Bs[cur], wm, wn, l15, quad, af, bf);
#pragma unroll
        for (int mt = 0; mt < 4; ++mt)
#pragma unroll
            for (int nt = 0; nt < 4; ++nt)
                acc[mt][nt] = __builtin_amdgcn_mfma_f32_16x16x32_f16(af[mt], bf[nt], acc[mt][nt], 0, 0, 0);
    }

    const int rbase = quad << 2;
#pragma unroll
    for (int mt = 0; mt < 4; ++mt) {
#pragma unroll
        for (int nt = 0; nt < 4; ++nt) {
            int gn = n0 + wn * 64 + nt * 16 + l15;
#pragma unroll
            for (int r = 0; r < 4; ++r) {
                int gm = m0 + wm * 64 + mt * 16 + rbase + r;
                int b = gm >> 11, t = gm & (TSEQ - 1);
                if (gn < CEMB) {
                    int h = gn >> 6, d = gn & 63;
                    q16[(((size_t)(b * NHEAD + h)) * TSEQ + t) * HD + d] =
                        (_Float16)(acc[mt][nt][r] * 8.0f);   // fold sqrt(hd)=8
                } else if (gn < 2 * CEMB) {
                    int c2 = gn - CEMB;
                    int h = c2 >> 6, d = c2 & 63;
                    k16[(((size_t)(b * NHEAD + h)) * TSEQ + t) * HD + d] =
                        (_Float16)acc[mt][nt][r];
                } else {
                    int c2 = gn - 2 * CEMB;
                    int h = c2 >> 6, d = c2 & 63;
                    v16[(((size_t)(b * NHEAD + h)) * HD + d) * TSEQ + t] =
                        (_Float16)acc[mt][nt][r];            // V^T
                }
            }
        }
    }
}

// ---------------------------------------------------------------------------
// Kernel 2: flash attention. S^T = K·Q^T so softmaxed P stays in registers in
// B-fragment layout for mfma_16x16x16f16 (O^T = V^T·P^T, zero LDS transpose).
// Paired q-tiles (x, 31-x); DMA double-buffered K/V; one barrier per k-tile.
// Unpadded 64x64 tiles, XOR swizzle pc = c ^ (row&7): DMA writes and frag
// reads both hit the wave64 bank minimum.
// ---------------------------------------------------------------------------
__device__ __forceinline__ void attn_tile(
    const half8& qf0, const half8& qf1,
    float& m_i, float& l_i, floatx4 (&o)[4],
    const _Float16* __restrict__ Ks, const _Float16* __restrict__ Vs,
    bool domask, int l15, int quad, int relq)
{
    floatx4 s[4];
#pragma unroll
    for (int nt = 0; nt < 4; ++nt) {
        int row = nt * 16 + l15;
        int pc0 = quad ^ (row & 7);
        half8 kf0 = *(const half8*)(Ks + row * 64 + pc0 * 8);
        half8 kf1 = *(const half8*)(Ks + row * 64 + (pc0 ^ 4) * 8);
        floatx4 z = (floatx4){0.f, 0.f, 0.f, 0.f};
        z = __builtin_amdgcn_mfma_f32_16x16x32_f16(kf0, qf0, z, 0, 0, 0);  // A=K
        z = __builtin_amdgcn_mfma_f32_16x16x32_f16(kf1, qf1, z, 0, 0, 0);  // B=Q
        s[nt] = z;   // S^T[key = nt*16+quad*4+r][q = l15]  (x8 folded into q)
    }
    if (domask) {
#pragma unroll
        for (int nt = 0; nt < 4; ++nt)
#pragma unroll
            for (int r = 0; r < 4; ++r)
                if (nt * 16 + quad * 4 + r > relq) s[nt][r] = -INFINITY;
    }
    float mx = m_i;
#pragma unroll
    for (int nt = 0; nt < 4; ++nt)
        mx = fmaxf(mx, fmaxf(fmaxf(s[nt][0], s[nt][1]), fmaxf(s[nt][2], s[nt][3])));
    mx = fmaxf(mx, __shfl_xor(mx, 16, 64));
    mx = fmaxf(mx, __shfl_xor(mx, 32, 64));
    float alpha = __expf(m_i - mx);
    m_i = mx;
    float rs = 0.f;
    half4 p[4];
#pragma unroll
    for (int nt = 0; nt < 4; ++nt) {
        float p0 = __expf(s[nt][0] - mx), p1 = __expf(s[nt][1] - mx);
        float p2 = __expf(s[nt][2] - mx), p3 = __expf(s[nt][3] - mx);
        rs += (p0 + p1) + (p2 + p3);
        p[nt] = (half4){ (_Float16)p0, (_Float16)p1, (_Float16)p2, (_Float16)p3 };
    }
    rs += __shfl_xor(rs, 16, 64);
    rs += __shfl_xor(rs, 32, 64);
    l_i = l_i * alpha + rs;
#pragma unroll
    for (int mt = 0; mt < 4; ++mt)
#pragma unroll
        for (int r = 0; r < 4; ++r) o[mt][r] *= alpha;
    // O^T += V^T · P^T : A = V^T half4 (contiguous keys), B = p[nt] (in regs)
#pragma unroll
    for (int mt = 0; mt < 4; ++mt) {
        int d = mt * 16 + l15;
#pragma unroll
        for (int nt = 0; nt < 4; ++nt) {
            int pc = (2 * nt + (quad >> 1)) ^ (d & 7);
            half4 vf = *(const half4*)(Vs + d * 64 + pc * 8 + (quad & 1) * 4);
            o[mt] = __builtin_amdgcn_mfma_f32_16x16x16f16(vf, p[nt], o[mt], 0, 0, 0);
        }
    }
}

__global__ __launch_bounds__(256)
void attn_fwd(const _Float16* __restrict__ q16, const _Float16* __restrict__ k16,
              const _Float16* __restrict__ v16, _Float16* __restrict__ o16)
{
    __shared__ __align__(16) _Float16 Ks[2][64 * 64];
    __shared__ __align__(16) _Float16 Vs[2][64 * 64];
    const int tid = threadIdx.x, lane = tid & 63, wave = tid >> 6;
    const int l15 = lane & 15, quad = lane >> 4;
    const int qtA = blockIdx.x;        // 0..15
    const int qtB = 31 - qtA;          // 31..16
    const int bh = blockIdx.y, b = bh >> 4, h = bh & 15;
    const int q0A = qtA * 64, q0B = qtB * 64;
    const _Float16* qp = q16 + (size_t)bh * TSEQ * HD;
    const _Float16* kp = k16 + (size_t)bh * TSEQ * HD;
    const _Float16* vp = v16 + (size_t)bh * HD * TSEQ;

    const int relq = wave * 16 + l15;          // q row within 64-tile
    half8 qA0 = *(const half8*)(qp + (size_t)(q0A + relq) * HD + quad * 8);
    half8 qA1 = *(const half8*)(qp + (size_t)(q0A + relq) * HD + 32 + quad * 8);
    half8 qB0 = *(const half8*)(qp + (size_t)(q0B + relq) * HD + quad * 8);
    half8 qB1 = *(const half8*)(qp + (size_t)(q0B + relq) * HD + 32 + quad * 8);

    float mA = -INFINITY, lA = 0.f, mB = -INFINITY, lB = 0.f;
    floatx4 oA[4], oB[4];
#pragma unroll
    for (int mt = 0; mt < 4; ++mt) { oA[mt] = (floatx4){0.f,0.f,0.f,0.f}; oB[mt] = (floatx4){0.f,0.f,0.f,0.f}; }

    // DMA staging: ci = p*256+tid (lane-contiguous); row = ci>>3, c = (ci&7)^(row&7)
#define STAGE_KV(kt0, buf)                                                     \
    {                                                                          \
        _Float16* kd = Ks[buf];                                                \
        _Float16* vd = Vs[buf];                                                \
        _Pragma("unroll")                                                      \
        for (int p = 0; p < 2; ++p) {                                          \
            int ci = p * 256 + tid;                                            \
            int row = ci >> 3;                                                 \
            int c = (ci & 7) ^ (row & 7);                                      \
            lds_dma16(kp + (size_t)((kt0) + row) * HD + c * 8, kd + ci * 8);   \
            lds_dma16(vp + (size_t)row * TSEQ + (kt0) + c * 8, vd + ci * 8);   \
        }                                                                      \
    }

    STAGE_KV(0, 0);
    for (int kt = 0; kt <= qtB; ++kt) {
        const int cur = kt & 1;
        __syncthreads();                       // drains DMA(kt) into buf[cur]
        if (kt < qtB) STAGE_KV((kt + 1) * 64, cur ^ 1);   // hides behind compute
        attn_tile(qB0, qB1, mB, lB, oB, Ks[cur], Vs[cur], (kt == qtB), l15, quad, relq);
        if (kt <= qtA)
            attn_tile(qA0, qA1, mA, lA, oA, Ks[cur], Vs[cur], (kt == qtA), l15, quad, relq);
    }
#undef STAGE_KV

    // epilogue: lane holds O^T[d = mt*16+quad*4+r][q = relq] -> half4 stores
    const float invA = 1.f / lA, invB = 1.f / lB;
    const size_t baseA = ((size_t)(b * TSEQ + q0A + relq)) * CEMB + h * HD + quad * 4;
    const size_t baseB = ((size_t)(b * TSEQ + q0B + relq)) * CEMB + h * HD + quad * 4;
#pragma unroll
    for (int mt = 0; mt < 4; ++mt) {
        half4 ha = { (_Float16)(oA[mt][0] * invA), (_Float16)(oA[mt][1] * invA),
                     (_Float16)(oA[mt][2] * invA), (_Float16)(oA[mt][3] * invA) };
        half4 hb = { (_Float16)(oB[mt][0] * invB), (_Float16)(oB[mt][1] * invB),
                     (_Float16)(oB[mt][2] * invB), (_Float16)(oB[mt][3] * invB) };
        *(half4*)(o16 + baseA + mt * 16) = ha;
        *(half4*)(o16 + baseB + mt * 16) = hb;
    }
}

// ---------------------------------------------------------------------------
// Kernel 3: y = attn16 @ Wp16^T + b_proj, fp32 out. Same dbuf DMA structure.
// ---------------------------------------------------------------------------
__global__ __launch_bounds__(256)
void proj_gemm(const _Float16* __restrict__ A, const _Float16* __restrict__ B,
               const float* __restrict__ bias, float* __restrict__ out)
{
    __shared__ __align__(16) _Float16 As[2][128 * 32];
    __shared__ __align__(16) _Float16 Bs[2][128 * 32];
    const int tid = threadIdx.x, lane = tid & 63, wave = tid >> 6;
    const int wm = wave & 1, wn = wave >> 1;
    const int m0 = blockIdx.y * 128, n0 = blockIdx.x * 128;
    const int l15 = lane & 15, quad = lane >> 4;

    floatx4 acc[4][4];
#pragma unroll
    for (int i = 0; i < 4; ++i)
#pragma unroll
        for (int j = 0; j < 4; ++j) acc[i][j] = (floatx4){0.f, 0.f, 0.f, 0.f};

    stage32(A, As[0], m0, 0, tid);
    stage32(B, Bs[0], n0, 0, tid);
    for (int kt = 0; kt < 32; ++kt) {
        const int cur = kt & 1;
        __syncthreads();
        if (kt < 31) {
            stage32(A, As[cur ^ 1], m0, (kt + 1) * 32, tid);
            stage32(B, Bs[cur ^ 1], n0, (kt + 1) * 32, tid);
        }
        half8 af[4], bf[4];
        gemm_frags(As[cur], Bs[cur], wm, wn, l15, quad, af, bf);
#pragma unroll
        for (int mt = 0; mt < 4; ++mt)
#pragma unroll
            for (int nt = 0; nt < 4; ++nt)
                acc[mt][nt] = __builtin_amdgcn_mfma_f32_16x16x32_f16(af[mt], bf[nt], acc[mt][nt], 0, 0, 0);
    }

    const int rbase = quad << 2;
#pragma unroll
    for (int mt = 0; mt < 4; ++mt)
#pragma unroll
        for (int nt = 0; nt < 4; ++nt) {
            int gn = n0 + wn * 64 + nt * 16 + l15;
            float bb = bias[gn];
#pragma unroll
            for (int r = 0; r < 4; ++r) {
                int gm = m0 + wm * 64 + mt * 16 + rbase + r;
                out[(size_t)gm * CEMB + gn] = acc[mt][nt][r] + bb;
            }
        }
}

// ---------------------------------------------------------------------------
extern "C" void kernel_launch(void* const* d_in, const int* in_sizes, int n_in,
                              void* d_out, int out_size, void* d_ws, size_t ws_size,
                              hipStream_t stream) {
    const float* x     = (const float*)d_in[0];
    const float* Wattn = (const float*)d_in[1];
    const float* Wproj = (const float*)d_in[2];
    const float* bproj = (const float*)d_in[3];
    float* out = (float*)d_out;

    const size_t nx  = (size_t)BATCH * TSEQ * CEMB;
    const size_t nwa = (size_t)3 * CEMB * CEMB;
    const size_t nwp = (size_t)CEMB * CEMB;
    const size_t per = (size_t)BATCH * NHEAD * TSEQ * HD;

    _Float16* x16    = (_Float16*)d_ws;
    _Float16* wa16   = x16 + nx;
    _Float16* wp16   = wa16 + nwa;
    _Float16* q16    = wp16 + nwp;
    _Float16* k16    = q16 + per;
    _Float16* v16    = k16 + per;
    _Float16* attn16 = x16;   // alias: x16 fully consumed before attn writes

    const int nconv = (int)((nx + nwa + nwp) / 4);
    cvt_fp16<<<nconv / 256, 256, 0, stream>>>(x, Wattn, Wproj, x16, wa16, wp16);
    qkv_gemm<<<dim3(3 * CEMB / 128, MROWS / 128), 256, 0, stream>>>(x16, wa16, q16, k16, v16);
    attn_fwd<<<dim3(16, BATCH * NHEAD), 256, 0, stream>>>(q16, k16, v16, attn16);
    proj_gemm<<<dim3(CEMB / 128, MROWS / 128), 256, 0, stream>>>(attn16, wp16, bproj, out);
}

// Round 6
// 302.074 us; speedup vs baseline: 1.4619x; 1.0735x over previous
//
#include <hip/hip_runtime.h>
#include <math.h>

#define BATCH 4
#define TSEQ  2048
#define CEMB  1024
#define NHEAD 16
#define HD    64
#define MROWS (BATCH * TSEQ)   // 8192
#define QSCALE 11.5415603271f  // 8 * log2(e): softmax runs in exp2 domain

typedef _Float16 half8 __attribute__((ext_vector_type(8)));
typedef _Float16 half4 __attribute__((ext_vector_type(4)));
typedef float    floatx4 __attribute__((ext_vector_type(4)));

#define GLOBAL_AS __attribute__((address_space(1)))
#define LDS_AS    __attribute__((address_space(3)))

__device__ __forceinline__ void lds_dma16(const _Float16* g, _Float16* l) {
    __builtin_amdgcn_global_load_lds((const GLOBAL_AS unsigned int*)g,
                                     (LDS_AS unsigned int*)l, 16, 0, 0);
}

// raw v_exp_f32 (2^x). VALU interlocks handle the hazard; exp2(-inf)=0.
__device__ __forceinline__ float fast_exp2(float x) {
    float r; asm("v_exp_f32 %0, %1" : "=v"(r) : "v"(x)); return r;
}

// ---------------------------------------------------------------------------
// Kernel 0: fp32 -> fp16 convert prepass (float4 -> half4)
// ---------------------------------------------------------------------------
__global__ __launch_bounds__(256)
void cvt_fp16(const float* __restrict__ x, const float* __restrict__ wa,
              const float* __restrict__ wp, _Float16* __restrict__ x16,
              _Float16* __restrict__ wa16, _Float16* __restrict__ wp16)
{
    const int n1 = (BATCH * TSEQ * CEMB) / 4;
    const int n2 = (3 * CEMB * CEMB) / 4;
    int i = blockIdx.x * 256 + threadIdx.x;
    const float* src; _Float16* dst; int j;
    if (i < n1)            { src = x;  dst = x16;  j = i; }
    else if (i < n1 + n2)  { src = wa; dst = wa16; j = i - n1; }
    else                   { src = wp; dst = wp16; j = i - n1 - n2; }
    float4 v = ((const float4*)src)[j];
    half4 h = { (_Float16)v.x, (_Float16)v.y, (_Float16)v.z, (_Float16)v.w };
    ((half4*)dst)[j] = h;
}

// ---------------------------------------------------------------------------
// GEMM staging: 128x32 fp16 tile, DMA, XOR swizzle c = pc ^ (row&3).
// ---------------------------------------------------------------------------
__device__ __forceinline__ void stage32(const _Float16* __restrict__ gbase,
                                        _Float16* __restrict__ lds,
                                        int row0, int kk, int tid)
{
#pragma unroll
    for (int p = 0; p < 2; ++p) {
        int ci  = p * 256 + tid;
        int row = ci >> 2, pcc = ci & 3;
        int c   = pcc ^ (row & 3);
        lds_dma16(gbase + (size_t)(row0 + row) * CEMB + kk + c * 8, lds + ci * 8);
    }
}

// ---------------------------------------------------------------------------
// Kernel 1: qkv = x16 @ Wa16^T. Blocks are pure-q (bx<8), pure-k (8..15) or
// pure-v (16..23). Epilogue stages C through LDS for coalesced half8 stores;
// v blocks transpose in LDS. q is pre-scaled by 8*log2e.
// ---------------------------------------------------------------------------
__global__ __launch_bounds__(256)
void qkv_gemm(const _Float16* __restrict__ A, const _Float16* __restrict__ B,
              _Float16* __restrict__ q16, _Float16* __restrict__ k16,
              _Float16* __restrict__ v16)
{
    __shared__ __align__(16) _Float16 smem[16384];   // 32 KB: dbuf tiles / C-tile
    const int tid = threadIdx.x, lane = tid & 63, wave = tid >> 6;
    const int wm = wave & 1, wn = wave >> 1;
    const int m0 = blockIdx.y * 128, n0 = blockIdx.x * 128;
    const int l15 = lane & 15, quad = lane >> 4;

    floatx4 acc[4][4];
#pragma unroll
    for (int i = 0; i < 4; ++i)
#pragma unroll
        for (int j = 0; j < 4; ++j) acc[i][j] = (floatx4){0.f, 0.f, 0.f, 0.f};

    stage32(A, smem, m0, 0, tid);
    stage32(B, smem + 8192, n0, 0, tid);
    for (int kt = 0; kt < 32; ++kt) {
        const int cur = kt & 1;
        _Float16* Asc = smem + cur * 4096;
        _Float16* Bsc = smem + 8192 + cur * 4096;
        __syncthreads();                      // drains DMA(kt)
        if (kt < 31) {
            stage32(A, smem + (cur ^ 1) * 4096, m0, (kt + 1) * 32, tid);
            stage32(B, smem + 8192 + (cur ^ 1) * 4096, n0, (kt + 1) * 32, tid);
        }
        half8 af[4], bf[4];
#pragma unroll
        for (int mt = 0; mt < 4; ++mt) {
            int row = wm * 64 + mt * 16 + l15;
            af[mt] = *(const half8*)(Asc + row * 32 + (quad ^ (row & 3)) * 8);
        }
#pragma unroll
        for (int nt = 0; nt < 4; ++nt) {
            int row = wn * 64 + nt * 16 + l15;
            bf[nt] = *(const half8*)(Bsc + row * 32 + (quad ^ (row & 3)) * 8);
        }
#pragma unroll
        for (int mt = 0; mt < 4; ++mt)
#pragma unroll
            for (int nt = 0; nt < 4; ++nt)
                acc[mt][nt] = __builtin_amdgcn_mfma_f32_16x16x32_f16(af[mt], bf[nt], acc[mt][nt], 0, 0, 0);
    }

    __syncthreads();                          // all frag reads done; reuse smem
    const int rbase = quad << 2;
    if (n0 < 2 * CEMB) {
        // --- q/k: C[t][n'] with chunk swizzle pc = (n>>3) ^ (t&15) ---
        const float scale = (n0 < CEMB) ? QSCALE : 1.0f;
#pragma unroll
        for (int mt = 0; mt < 4; ++mt)
#pragma unroll
            for (int nt = 0; nt < 4; ++nt)
#pragma unroll
                for (int r = 0; r < 4; ++r) {
                    int t = wm * 64 + mt * 16 + rbase + r;
                    int n = wn * 64 + nt * 16 + l15;
                    int pc = (n >> 3) ^ (t & 15);
                    smem[t * 128 + pc * 8 + (n & 7)] = (_Float16)(acc[mt][nt][r] * scale);
                }
        __syncthreads();
        const int chunk = tid & 7;
#pragma unroll
        for (int i = 0; i < 8; ++i) {
            int gr = (tid >> 3) + i * 32;     // 0..255: (seg,t)
            int seg = gr >> 7, t = gr & 127;
            int pc = (seg * 8 + chunk) ^ (t & 15);
            half8 v = *(const half8*)(smem + t * 128 + pc * 8);
            int gm = m0 + t, b = gm >> 11, tt = gm & (TSEQ - 1);
            int gnb = n0 + seg * 64;
            _Float16* dst;
            if (n0 < CEMB) {
                int h = gnb >> 6;
                dst = q16 + (((size_t)(b * NHEAD + h)) * TSEQ + tt) * HD;
            } else {
                int h = (gnb - CEMB) >> 6;
                dst = k16 + (((size_t)(b * NHEAD + h)) * TSEQ + tt) * HD;
            }
            *(half8*)(dst + chunk * 8) = v;
        }
    } else {
        // --- v: transpose in LDS: C[n'][t] with pc = (t>>3) ^ (n&15) ---
#pragma unroll
        for (int mt = 0; mt < 4; ++mt)
#pragma unroll
            for (int nt = 0; nt < 4; ++nt)
#pragma unroll
                for (int r = 0; r < 4; ++r) {
                    int t = wm * 64 + mt * 16 + rbase + r;
                    int n = wn * 64 + nt * 16 + l15;
                    int pc = (t >> 3) ^ (n & 15);
                    smem[n * 128 + pc * 8 + (t & 7)] = (_Float16)acc[mt][nt][r];
                }
        __syncthreads();
        const int chunk = tid & 15;           // 16 chunks of 8 along t
        const int b = m0 >> 11, tblk = m0 & (TSEQ - 1);
#pragma unroll
        for (int i = 0; i < 8; ++i) {
            int row = (tid >> 4) + i * 16;    // n' 0..127
            int pc = chunk ^ (row & 15);
            half8 v = *(const half8*)(smem + row * 128 + pc * 8);
            int c2 = n0 - 2 * CEMB + row;
            int h = c2 >> 6, d = c2 & 63;
            *(half8*)(v16 + (((size_t)(b * NHEAD + h)) * HD + d) * TSEQ + tblk + chunk * 8) = v;
        }
    }
}

// ---------------------------------------------------------------------------
// Kernel 2: flash attention (S^T = K·Q^T; P in registers in B-layout for
// mfma_16x16x16f16; O^T = V^T·P^T). exp2-domain softmax (scale folded in q).
// Paired q-tiles; DMA double-buffered K/V; one barrier per k-tile.
// ---------------------------------------------------------------------------
__device__ __forceinline__ void attn_tile(
    const half8& qf0, const half8& qf1,
    float& m_i, float& l_i, floatx4 (&o)[4],
    const _Float16* __restrict__ Ks, const _Float16* __restrict__ Vs,
    bool domask, int l15, int quad, int relq)
{
    floatx4 s[4];
#pragma unroll
    for (int nt = 0; nt < 4; ++nt) {
        int row = nt * 16 + l15;
        int pc0 = quad ^ (row & 7);
        half8 kf0 = *(const half8*)(Ks + row * 64 + pc0 * 8);
        half8 kf1 = *(const half8*)(Ks + row * 64 + (pc0 ^ 4) * 8);
        floatx4 z = (floatx4){0.f, 0.f, 0.f, 0.f};
        z = __builtin_amdgcn_mfma_f32_16x16x32_f16(kf0, qf0, z, 0, 0, 0);
        z = __builtin_amdgcn_mfma_f32_16x16x32_f16(kf1, qf1, z, 0, 0, 0);
        s[nt] = z;   // S^T[key = nt*16+quad*4+r][q = l15], exp2-domain logits
    }
    if (domask) {
#pragma unroll
        for (int nt = 0; nt < 4; ++nt)
#pragma unroll
            for (int r = 0; r < 4; ++r)
                if (nt * 16 + quad * 4 + r > relq) s[nt][r] = -INFINITY;
    }
    float mx = m_i;
#pragma unroll
    for (int nt = 0; nt < 4; ++nt)
        mx = fmaxf(mx, fmaxf(fmaxf(s[nt][0], s[nt][1]), fmaxf(s[nt][2], s[nt][3])));
    mx = fmaxf(mx, __shfl_xor(mx, 16, 64));
    mx = fmaxf(mx, __shfl_xor(mx, 32, 64));
    float alpha = fast_exp2(m_i - mx);
    m_i = mx;
    float rs = 0.f;
    half4 p[4];
#pragma unroll
    for (int nt = 0; nt < 4; ++nt) {
        float p0 = fast_exp2(s[nt][0] - mx), p1 = fast_exp2(s[nt][1] - mx);
        float p2 = fast_exp2(s[nt][2] - mx), p3 = fast_exp2(s[nt][3] - mx);
        rs += (p0 + p1) + (p2 + p3);
        p[nt] = (half4){ (_Float16)p0, (_Float16)p1, (_Float16)p2, (_Float16)p3 };
    }
    rs += __shfl_xor(rs, 16, 64);
    rs += __shfl_xor(rs, 32, 64);
    l_i = l_i * alpha + rs;
#pragma unroll
    for (int mt = 0; mt < 4; ++mt)
#pragma unroll
        for (int r = 0; r < 4; ++r) o[mt][r] *= alpha;
#pragma unroll
    for (int mt = 0; mt < 4; ++mt) {
        int d = mt * 16 + l15;
#pragma unroll
        for (int nt = 0; nt < 4; ++nt) {
            int pc = (2 * nt + (quad >> 1)) ^ (d & 7);
            half4 vf = *(const half4*)(Vs + d * 64 + pc * 8 + (quad & 1) * 4);
            o[mt] = __builtin_amdgcn_mfma_f32_16x16x16f16(vf, p[nt], o[mt], 0, 0, 0);
        }
    }
}

__global__ __launch_bounds__(256)
void attn_fwd(const _Float16* __restrict__ q16, const _Float16* __restrict__ k16,
              const _Float16* __restrict__ v16, _Float16* __restrict__ o16)
{
    __shared__ __align__(16) _Float16 Ks[2][64 * 64];
    __shared__ __align__(16) _Float16 Vs[2][64 * 64];
    const int tid = threadIdx.x, lane = tid & 63, wave = tid >> 6;
    const int l15 = lane & 15, quad = lane >> 4;
    const int qtA = blockIdx.x;        // 0..15
    const int qtB = 31 - qtA;          // 31..16
    const int bh = blockIdx.y, b = bh >> 4, h = bh & 15;
    const int q0A = qtA * 64, q0B = qtB * 64;
    const _Float16* qp = q16 + (size_t)bh * TSEQ * HD;
    const _Float16* kp = k16 + (size_t)bh * TSEQ * HD;
    const _Float16* vp = v16 + (size_t)bh * HD * TSEQ;

    const int relq = wave * 16 + l15;
    half8 qA0 = *(const half8*)(qp + (size_t)(q0A + relq) * HD + quad * 8);
    half8 qA1 = *(const half8*)(qp + (size_t)(q0A + relq) * HD + 32 + quad * 8);
    half8 qB0 = *(const half8*)(qp + (size_t)(q0B + relq) * HD + quad * 8);
    half8 qB1 = *(const half8*)(qp + (size_t)(q0B + relq) * HD + 32 + quad * 8);

    float mA = -INFINITY, lA = 0.f, mB = -INFINITY, lB = 0.f;
    floatx4 oA[4], oB[4];
#pragma unroll
    for (int mt = 0; mt < 4; ++mt) { oA[mt] = (floatx4){0.f,0.f,0.f,0.f}; oB[mt] = (floatx4){0.f,0.f,0.f,0.f}; }

#define STAGE_KV(kt0, buf)                                                     \
    {                                                                          \
        _Float16* kd = Ks[buf];                                                \
        _Float16* vd = Vs[buf];                                                \
        _Pragma("unroll")                                                      \
        for (int p = 0; p < 2; ++p) {                                          \
            int ci = p * 256 + tid;                                            \
            int row = ci >> 3;                                                 \
            int c = (ci & 7) ^ (row & 7);                                      \
            lds_dma16(kp + (size_t)((kt0) + row) * HD + c * 8, kd + ci * 8);   \
            lds_dma16(vp + (size_t)row * TSEQ + (kt0) + c * 8, vd + ci * 8);   \
        }                                                                      \
    }

    STAGE_KV(0, 0);
    for (int kt = 0; kt <= qtB; ++kt) {
        const int cur = kt & 1;
        __syncthreads();
        if (kt < qtB) STAGE_KV((kt + 1) * 64, cur ^ 1);
        attn_tile(qB0, qB1, mB, lB, oB, Ks[cur], Vs[cur], (kt == qtB), l15, quad, relq);
        if (kt <= qtA)
            attn_tile(qA0, qA1, mA, lA, oA, Ks[cur], Vs[cur], (kt == qtA), l15, quad, relq);
    }
#undef STAGE_KV

    const float invA = 1.f / lA, invB = 1.f / lB;
    const size_t baseA = ((size_t)(b * TSEQ + q0A + relq)) * CEMB + h * HD + quad * 4;
    const size_t baseB = ((size_t)(b * TSEQ + q0B + relq)) * CEMB + h * HD + quad * 4;
#pragma unroll
    for (int mt = 0; mt < 4; ++mt) {
        half4 ha = { (_Float16)(oA[mt][0] * invA), (_Float16)(oA[mt][1] * invA),
                     (_Float16)(oA[mt][2] * invA), (_Float16)(oA[mt][3] * invA) };
        half4 hb = { (_Float16)(oB[mt][0] * invB), (_Float16)(oB[mt][1] * invB),
                     (_Float16)(oB[mt][2] * invB), (_Float16)(oB[mt][3] * invB) };
        *(half4*)(o16 + baseA + mt * 16) = ha;
        *(half4*)(o16 + baseB + mt * 16) = hb;
    }
}

// ---------------------------------------------------------------------------
// Kernel 3: y = attn16 @ Wp16^T + b_proj, fp32 out. 64x128 tile -> 1024
// blocks (4/CU) for latency hiding. Same dbuf DMA structure.
// ---------------------------------------------------------------------------
__global__ __launch_bounds__(256)
void proj_gemm(const _Float16* __restrict__ A, const _Float16* __restrict__ B,
               const float* __restrict__ bias, float* __restrict__ out)
{
    __shared__ __align__(16) _Float16 As2[2][64 * 32];
    __shared__ __align__(16) _Float16 Bs2[2][128 * 32];
    const int tid = threadIdx.x, lane = tid & 63, wave = tid >> 6;
    const int wm = wave & 1, wn = wave >> 1;
    const int m0 = blockIdx.y * 64, n0 = blockIdx.x * 128;
    const int l15 = lane & 15, quad = lane >> 4;

    floatx4 acc[2][4];
#pragma unroll
    for (int i = 0; i < 2; ++i)
#pragma unroll
        for (int j = 0; j < 4; ++j) acc[i][j] = (floatx4){0.f, 0.f, 0.f, 0.f};

    // A-tile: 64 rows x 4 chunks = 256 -> 1 DMA/thread
#define STAGE_A(kk, buf)                                                       \
    {                                                                          \
        int row = tid >> 2, c = (tid & 3) ^ (row & 3);                         \
        lds_dma16(A + (size_t)(m0 + row) * CEMB + (kk) + c * 8,                \
                  As2[buf] + tid * 8);                                         \
    }

    STAGE_A(0, 0);
    stage32(B, Bs2[0], n0, 0, tid);
    for (int kt = 0; kt < 32; ++kt) {
        const int cur = kt & 1;
        __syncthreads();
        if (kt < 31) {
            STAGE_A((kt + 1) * 32, cur ^ 1);
            stage32(B, Bs2[cur ^ 1], n0, (kt + 1) * 32, tid);
        }
        half8 af[2], bf[4];
#pragma unroll
        for (int mt = 0; mt < 2; ++mt) {
            int row = wm * 32 + mt * 16 + l15;
            af[mt] = *(const half8*)(As2[cur] + row * 32 + (quad ^ (row & 3)) * 8);
        }
#pragma unroll
        for (int nt = 0; nt < 4; ++nt) {
            int row = wn * 64 + nt * 16 + l15;
            bf[nt] = *(const half8*)(Bs2[cur] + row * 32 + (quad ^ (row & 3)) * 8);
        }
#pragma unroll
        for (int mt = 0; mt < 2; ++mt)
#pragma unroll
            for (int nt = 0; nt < 4; ++nt)
                acc[mt][nt] = __builtin_amdgcn_mfma_f32_16x16x32_f16(af[mt], bf[nt], acc[mt][nt], 0, 0, 0);
    }
#undef STAGE_A

    const int rbase = quad << 2;
#pragma unroll
    for (int mt = 0; mt < 2; ++mt)
#pragma unroll
        for (int nt = 0; nt < 4; ++nt) {
            int gn = n0 + wn * 64 + nt * 16 + l15;
            float bb = bias[gn];
#pragma unroll
            for (int r = 0; r < 4; ++r) {
                int gm = m0 + wm * 32 + mt * 16 + rbase + r;
                out[(size_t)gm * CEMB + gn] = acc[mt][nt][r] + bb;
            }
        }
}

// ---------------------------------------------------------------------------
extern "C" void kernel_launch(void* const* d_in, const int* in_sizes, int n_in,
                              void* d_out, int out_size, void* d_ws, size_t ws_size,
                              hipStream_t stream) {
    const float* x     = (const float*)d_in[0];
    const float* Wattn = (const float*)d_in[1];
    const float* Wproj = (const float*)d_in[2];
    const float* bproj = (const float*)d_in[3];
    float* out = (float*)d_out;

    const size_t nx  = (size_t)BATCH * TSEQ * CEMB;
    const size_t nwa = (size_t)3 * CEMB * CEMB;
    const size_t nwp = (size_t)CEMB * CEMB;
    const size_t per = (size_t)BATCH * NHEAD * TSEQ * HD;

    _Float16* x16    = (_Float16*)d_ws;
    _Float16* wa16   = x16 + nx;
    _Float16* wp16   = wa16 + nwa;
    _Float16* q16    = wp16 + nwp;
    _Float16* k16    = q16 + per;
    _Float16* v16    = k16 + per;
    _Float16* attn16 = x16;   // alias: x16 fully consumed before attn writes

    const int nconv = (int)((nx + nwa + nwp) / 4);
    cvt_fp16<<<nconv / 256, 256, 0, stream>>>(x, Wattn, Wproj, x16, wa16, wp16);
    qkv_gemm<<<dim3(3 * CEMB / 128, MROWS / 128), 256, 0, stream>>>(x16, wa16, q16, k16, v16);
    attn_fwd<<<dim3(16, BATCH * NHEAD), 256, 0, stream>>>(q16, k16, v16, attn16);
    proj_gemm<<<dim3(CEMB / 128, MROWS / 64), 256, 0, stream>>>(attn16, wp16, bproj, out);
}

// Round 7
// 293.563 us; speedup vs baseline: 1.5043x; 1.0290x over previous
//
#include <hip/hip_runtime.h>
#include <math.h>

#define BATCH 4
#define TSEQ  2048
#define CEMB  1024
#define NHEAD 16
#define HD    64
#define MROWS (BATCH * TSEQ)   // 8192
#define QSCALE 11.5415603271f  // 8 * log2(e): softmax runs in exp2 domain

typedef _Float16 half8 __attribute__((ext_vector_type(8)));
typedef _Float16 half4 __attribute__((ext_vector_type(4)));
typedef float    floatx4 __attribute__((ext_vector_type(4)));

#define GLOBAL_AS __attribute__((address_space(1)))
#define LDS_AS    __attribute__((address_space(3)))

__device__ __forceinline__ void lds_dma16(const _Float16* g, _Float16* l) {
    __builtin_amdgcn_global_load_lds((const GLOBAL_AS unsigned int*)g,
                                     (LDS_AS unsigned int*)l, 16, 0, 0);
}

// raw v_exp_f32 (2^x). VALU interlocks handle the hazard; exp2(-inf)=0.
__device__ __forceinline__ float fast_exp2(float x) {
    float r; asm("v_exp_f32 %0, %1" : "=v"(r) : "v"(x)); return r;
}

// ---------------------------------------------------------------------------
// Kernel 0: fp32 -> fp16 convert prepass (float4 -> half4)
// ---------------------------------------------------------------------------
__global__ __launch_bounds__(256)
void cvt_fp16(const float* __restrict__ x, const float* __restrict__ wa,
              const float* __restrict__ wp, _Float16* __restrict__ x16,
              _Float16* __restrict__ wa16, _Float16* __restrict__ wp16)
{
    const int n1 = (BATCH * TSEQ * CEMB) / 4;
    const int n2 = (3 * CEMB * CEMB) / 4;
    int i = blockIdx.x * 256 + threadIdx.x;
    const float* src; _Float16* dst; int j;
    if (i < n1)            { src = x;  dst = x16;  j = i; }
    else if (i < n1 + n2)  { src = wa; dst = wa16; j = i - n1; }
    else                   { src = wp; dst = wp16; j = i - n1 - n2; }
    float4 v = ((const float4*)src)[j];
    half4 h = { (_Float16)v.x, (_Float16)v.y, (_Float16)v.z, (_Float16)v.w };
    ((half4*)dst)[j] = h;
}

// ---------------------------------------------------------------------------
// GEMM staging: 128x32 fp16 tile, DMA, XOR swizzle c = pc ^ (row&3).
// ---------------------------------------------------------------------------
__device__ __forceinline__ void stage32(const _Float16* __restrict__ gbase,
                                        _Float16* __restrict__ lds,
                                        int row0, int kk, int tid)
{
#pragma unroll
    for (int p = 0; p < 2; ++p) {
        int ci  = p * 256 + tid;
        int row = ci >> 2, pcc = ci & 3;
        int c   = pcc ^ (row & 3);
        lds_dma16(gbase + (size_t)(row0 + row) * CEMB + kk + c * 8, lds + ci * 8);
    }
}

// ---------------------------------------------------------------------------
// Kernel 1: qkv = x16 @ Wa16^T. Epilogue stages C through LDS for coalesced
// half8 stores; v blocks transpose in LDS. q is pre-scaled by 8*log2e.
// ---------------------------------------------------------------------------
__global__ __launch_bounds__(256)
void qkv_gemm(const _Float16* __restrict__ A, const _Float16* __restrict__ B,
              _Float16* __restrict__ q16, _Float16* __restrict__ k16,
              _Float16* __restrict__ v16)
{
    __shared__ __align__(16) _Float16 smem[16384];   // 32 KB: dbuf tiles / C-tile
    const int tid = threadIdx.x, lane = tid & 63, wave = tid >> 6;
    const int wm = wave & 1, wn = wave >> 1;
    const int m0 = blockIdx.y * 128, n0 = blockIdx.x * 128;
    const int l15 = lane & 15, quad = lane >> 4;

    floatx4 acc[4][4];
#pragma unroll
    for (int i = 0; i < 4; ++i)
#pragma unroll
        for (int j = 0; j < 4; ++j) acc[i][j] = (floatx4){0.f, 0.f, 0.f, 0.f};

    stage32(A, smem, m0, 0, tid);
    stage32(B, smem + 8192, n0, 0, tid);
    for (int kt = 0; kt < 32; ++kt) {
        const int cur = kt & 1;
        _Float16* Asc = smem + cur * 4096;
        _Float16* Bsc = smem + 8192 + cur * 4096;
        __syncthreads();                      // drains DMA(kt)
        if (kt < 31) {
            stage32(A, smem + (cur ^ 1) * 4096, m0, (kt + 1) * 32, tid);
            stage32(B, smem + 8192 + (cur ^ 1) * 4096, n0, (kt + 1) * 32, tid);
        }
        half8 af[4], bf[4];
#pragma unroll
        for (int mt = 0; mt < 4; ++mt) {
            int row = wm * 64 + mt * 16 + l15;
            af[mt] = *(const half8*)(Asc + row * 32 + (quad ^ (row & 3)) * 8);
        }
#pragma unroll
        for (int nt = 0; nt < 4; ++nt) {
            int row = wn * 64 + nt * 16 + l15;
            bf[nt] = *(const half8*)(Bsc + row * 32 + (quad ^ (row & 3)) * 8);
        }
#pragma unroll
        for (int mt = 0; mt < 4; ++mt)
#pragma unroll
            for (int nt = 0; nt < 4; ++nt)
                acc[mt][nt] = __builtin_amdgcn_mfma_f32_16x16x32_f16(af[mt], bf[nt], acc[mt][nt], 0, 0, 0);
    }

    __syncthreads();                          // all frag reads done; reuse smem
    const int rbase = quad << 2;
    if (n0 < 2 * CEMB) {
        // --- q/k: C[t][n'] with chunk swizzle pc = (n>>3) ^ (t&15) ---
        const float scale = (n0 < CEMB) ? QSCALE : 1.0f;
#pragma unroll
        for (int mt = 0; mt < 4; ++mt)
#pragma unroll
            for (int nt = 0; nt < 4; ++nt)
#pragma unroll
                for (int r = 0; r < 4; ++r) {
                    int t = wm * 64 + mt * 16 + rbase + r;
                    int n = wn * 64 + nt * 16 + l15;
                    int pc = (n >> 3) ^ (t & 15);
                    smem[t * 128 + pc * 8 + (n & 7)] = (_Float16)(acc[mt][nt][r] * scale);
                }
        __syncthreads();
        const int chunk = tid & 7;
#pragma unroll
        for (int i = 0; i < 8; ++i) {
            int gr = (tid >> 3) + i * 32;     // 0..255: (seg,t)
            int seg = gr >> 7, t = gr & 127;
            int pc = (seg * 8 + chunk) ^ (t & 15);
            half8 v = *(const half8*)(smem + t * 128 + pc * 8);
            int gm = m0 + t, b = gm >> 11, tt = gm & (TSEQ - 1);
            int gnb = n0 + seg * 64;
            _Float16* dst;
            if (n0 < CEMB) {
                int h = gnb >> 6;
                dst = q16 + (((size_t)(b * NHEAD + h)) * TSEQ + tt) * HD;
            } else {
                int h = (gnb - CEMB) >> 6;
                dst = k16 + (((size_t)(b * NHEAD + h)) * TSEQ + tt) * HD;
            }
            *(half8*)(dst + chunk * 8) = v;
        }
    } else {
        // --- v: transpose in LDS: C[n'][t] with pc = (t>>3) ^ (n&15) ---
#pragma unroll
        for (int mt = 0; mt < 4; ++mt)
#pragma unroll
            for (int nt = 0; nt < 4; ++nt)
#pragma unroll
                for (int r = 0; r < 4; ++r) {
                    int t = wm * 64 + mt * 16 + rbase + r;
                    int n = wn * 64 + nt * 16 + l15;
                    int pc = (t >> 3) ^ (n & 15);
                    smem[n * 128 + pc * 8 + (t & 7)] = (_Float16)acc[mt][nt][r];
                }
        __syncthreads();
        const int chunk = tid & 15;           // 16 chunks of 8 along t
        const int b = m0 >> 11, tblk = m0 & (TSEQ - 1);
#pragma unroll
        for (int i = 0; i < 8; ++i) {
            int row = (tid >> 4) + i * 16;    // n' 0..127
            int pc = chunk ^ (row & 15);
            half8 v = *(const half8*)(smem + row * 128 + pc * 8);
            int c2 = n0 - 2 * CEMB + row;
            int h = c2 >> 6, d = c2 & 63;
            *(half8*)(v16 + (((size_t)(b * NHEAD + h)) * HD + d) * TSEQ + tblk + chunk * 8) = v;
        }
    }
}

// ---------------------------------------------------------------------------
// Kernel 2: flash attention. S^T = K·Q^T; P stays in registers in B-layout
// for mfma_16x16x16f16 (O^T = V^T·P^T). Two phases: dual-tile (A+B share K/V
// fragments, interleaved for 2x ILP on the latency-bound chain), then B-only.
// ---------------------------------------------------------------------------
__device__ __forceinline__ void attn_tile(
    const half8& qf0, const half8& qf1,
    float& m_i, float& l_i, floatx4 (&o)[4],
    const _Float16* __restrict__ Ks, const _Float16* __restrict__ Vs,
    bool domask, int l15, int quad, int relq)
{
    floatx4 s[4];
#pragma unroll
    for (int nt = 0; nt < 4; ++nt) {
        int row = nt * 16 + l15;
        int pc0 = quad ^ (row & 7);
        half8 kf0 = *(const half8*)(Ks + row * 64 + pc0 * 8);
        half8 kf1 = *(const half8*)(Ks + row * 64 + (pc0 ^ 4) * 8);
        floatx4 z = (floatx4){0.f, 0.f, 0.f, 0.f};
        z = __builtin_amdgcn_mfma_f32_16x16x32_f16(kf0, qf0, z, 0, 0, 0);
        z = __builtin_amdgcn_mfma_f32_16x16x32_f16(kf1, qf1, z, 0, 0, 0);
        s[nt] = z;
    }
    if (domask) {
#pragma unroll
        for (int nt = 0; nt < 4; ++nt)
#pragma unroll
            for (int r = 0; r < 4; ++r)
                if (nt * 16 + quad * 4 + r > relq) s[nt][r] = -INFINITY;
    }
    float mx = m_i;
#pragma unroll
    for (int nt = 0; nt < 4; ++nt)
        mx = fmaxf(mx, fmaxf(fmaxf(s[nt][0], s[nt][1]), fmaxf(s[nt][2], s[nt][3])));
    mx = fmaxf(mx, __shfl_xor(mx, 16, 64));
    mx = fmaxf(mx, __shfl_xor(mx, 32, 64));
    float alpha = fast_exp2(m_i - mx);
    m_i = mx;
    float rs = 0.f;
    half4 p[4];
#pragma unroll
    for (int nt = 0; nt < 4; ++nt) {
        float p0 = fast_exp2(s[nt][0] - mx), p1 = fast_exp2(s[nt][1] - mx);
        float p2 = fast_exp2(s[nt][2] - mx), p3 = fast_exp2(s[nt][3] - mx);
        rs += (p0 + p1) + (p2 + p3);
        p[nt] = (half4){ (_Float16)p0, (_Float16)p1, (_Float16)p2, (_Float16)p3 };
    }
    rs += __shfl_xor(rs, 16, 64);
    rs += __shfl_xor(rs, 32, 64);
    l_i = l_i * alpha + rs;
#pragma unroll
    for (int mt = 0; mt < 4; ++mt)
#pragma unroll
        for (int r = 0; r < 4; ++r) o[mt][r] *= alpha;
#pragma unroll
    for (int mt = 0; mt < 4; ++mt) {
        int d = mt * 16 + l15;
#pragma unroll
        for (int nt = 0; nt < 4; ++nt) {
            int pc = (2 * nt + (quad >> 1)) ^ (d & 7);
            half4 vf = *(const half4*)(Vs + d * 64 + pc * 8 + (quad & 1) * 4);
            o[mt] = __builtin_amdgcn_mfma_f32_16x16x16f16(vf, p[nt], o[mt], 0, 0, 0);
        }
    }
}

// dual-tile body: A and B interleaved, shared K/V fragments. B never masked
// here (kt <= qtA < qtB); A masked iff kt == qtA.
__device__ __forceinline__ void attn_tile2(
    const half8& qA0, const half8& qA1, const half8& qB0, const half8& qB1,
    float& mAi, float& lAi, floatx4 (&oA)[4],
    float& mBi, float& lBi, floatx4 (&oB)[4],
    const _Float16* __restrict__ Ks, const _Float16* __restrict__ Vs,
    bool maskA, int l15, int quad, int relq)
{
    floatx4 sA[4], sB[4];
#pragma unroll
    for (int nt = 0; nt < 4; ++nt) {
        int row = nt * 16 + l15;
        int pc0 = quad ^ (row & 7);
        half8 kf0 = *(const half8*)(Ks + row * 64 + pc0 * 8);
        half8 kf1 = *(const half8*)(Ks + row * 64 + (pc0 ^ 4) * 8);
        floatx4 zA = (floatx4){0.f, 0.f, 0.f, 0.f};
        floatx4 zB = (floatx4){0.f, 0.f, 0.f, 0.f};
        zA = __builtin_amdgcn_mfma_f32_16x16x32_f16(kf0, qA0, zA, 0, 0, 0);
        zB = __builtin_amdgcn_mfma_f32_16x16x32_f16(kf0, qB0, zB, 0, 0, 0);
        zA = __builtin_amdgcn_mfma_f32_16x16x32_f16(kf1, qA1, zA, 0, 0, 0);
        zB = __builtin_amdgcn_mfma_f32_16x16x32_f16(kf1, qB1, zB, 0, 0, 0);
        sA[nt] = zA; sB[nt] = zB;
    }
    if (maskA) {
#pragma unroll
        for (int nt = 0; nt < 4; ++nt)
#pragma unroll
            for (int r = 0; r < 4; ++r)
                if (nt * 16 + quad * 4 + r > relq) sA[nt][r] = -INFINITY;
    }
    // interleaved max reductions (two independent shuffle chains)
    float mxA = mAi, mxB = mBi;
#pragma unroll
    for (int nt = 0; nt < 4; ++nt) {
        mxA = fmaxf(mxA, fmaxf(fmaxf(sA[nt][0], sA[nt][1]), fmaxf(sA[nt][2], sA[nt][3])));
        mxB = fmaxf(mxB, fmaxf(fmaxf(sB[nt][0], sB[nt][1]), fmaxf(sB[nt][2], sB[nt][3])));
    }
    mxA = fmaxf(mxA, __shfl_xor(mxA, 16, 64));
    mxB = fmaxf(mxB, __shfl_xor(mxB, 16, 64));
    mxA = fmaxf(mxA, __shfl_xor(mxA, 32, 64));
    mxB = fmaxf(mxB, __shfl_xor(mxB, 32, 64));
    float alA = fast_exp2(mAi - mxA);
    float alB = fast_exp2(mBi - mxB);
    mAi = mxA; mBi = mxB;
    float rsA = 0.f, rsB = 0.f;
    half4 pA[4], pB[4];
#pragma unroll
    for (int nt = 0; nt < 4; ++nt) {
        float a0 = fast_exp2(sA[nt][0] - mxA), b0 = fast_exp2(sB[nt][0] - mxB);
        float a1 = fast_exp2(sA[nt][1] - mxA), b1 = fast_exp2(sB[nt][1] - mxB);
        float a2 = fast_exp2(sA[nt][2] - mxA), b2 = fast_exp2(sB[nt][2] - mxB);
        float a3 = fast_exp2(sA[nt][3] - mxA), b3 = fast_exp2(sB[nt][3] - mxB);
        rsA += (a0 + a1) + (a2 + a3);
        rsB += (b0 + b1) + (b2 + b3);
        pA[nt] = (half4){ (_Float16)a0, (_Float16)a1, (_Float16)a2, (_Float16)a3 };
        pB[nt] = (half4){ (_Float16)b0, (_Float16)b1, (_Float16)b2, (_Float16)b3 };
    }
    rsA += __shfl_xor(rsA, 16, 64);
    rsB += __shfl_xor(rsB, 16, 64);
    rsA += __shfl_xor(rsA, 32, 64);
    rsB += __shfl_xor(rsB, 32, 64);
    lAi = lAi * alA + rsA;
    lBi = lBi * alB + rsB;
#pragma unroll
    for (int mt = 0; mt < 4; ++mt)
#pragma unroll
        for (int r = 0; r < 4; ++r) { oA[mt][r] *= alA; oB[mt][r] *= alB; }
    // PV with shared V fragments
#pragma unroll
    for (int mt = 0; mt < 4; ++mt) {
        int d = mt * 16 + l15;
#pragma unroll
        for (int nt = 0; nt < 4; ++nt) {
            int pc = (2 * nt + (quad >> 1)) ^ (d & 7);
            half4 vf = *(const half4*)(Vs + d * 64 + pc * 8 + (quad & 1) * 4);
            oA[mt] = __builtin_amdgcn_mfma_f32_16x16x16f16(vf, pA[nt], oA[mt], 0, 0, 0);
            oB[mt] = __builtin_amdgcn_mfma_f32_16x16x16f16(vf, pB[nt], oB[mt], 0, 0, 0);
        }
    }
}

__global__ __launch_bounds__(256)
void attn_fwd(const _Float16* __restrict__ q16, const _Float16* __restrict__ k16,
              const _Float16* __restrict__ v16, _Float16* __restrict__ o16)
{
    __shared__ __align__(16) _Float16 Ks[2][64 * 64];
    __shared__ __align__(16) _Float16 Vs[2][64 * 64];
    const int tid = threadIdx.x, lane = tid & 63, wave = tid >> 6;
    const int l15 = lane & 15, quad = lane >> 4;
    const int qtA = blockIdx.x;        // 0..15
    const int qtB = 31 - qtA;          // 31..16
    const int bh = blockIdx.y, b = bh >> 4, h = bh & 15;
    const int q0A = qtA * 64, q0B = qtB * 64;
    const _Float16* qp = q16 + (size_t)bh * TSEQ * HD;
    const _Float16* kp = k16 + (size_t)bh * TSEQ * HD;
    const _Float16* vp = v16 + (size_t)bh * HD * TSEQ;

    const int relq = wave * 16 + l15;
    half8 qA0 = *(const half8*)(qp + (size_t)(q0A + relq) * HD + quad * 8);
    half8 qA1 = *(const half8*)(qp + (size_t)(q0A + relq) * HD + 32 + quad * 8);
    half8 qB0 = *(const half8*)(qp + (size_t)(q0B + relq) * HD + quad * 8);
    half8 qB1 = *(const half8*)(qp + (size_t)(q0B + relq) * HD + 32 + quad * 8);

    float mA = -INFINITY, lA = 0.f, mB = -INFINITY, lB = 0.f;
    floatx4 oA[4], oB[4];
#pragma unroll
    for (int mt = 0; mt < 4; ++mt) { oA[mt] = (floatx4){0.f,0.f,0.f,0.f}; oB[mt] = (floatx4){0.f,0.f,0.f,0.f}; }

#define STAGE_KV(kt0, buf)                                                     \
    {                                                                          \
        _Float16* kd = Ks[buf];                                                \
        _Float16* vd = Vs[buf];                                                \
        _Pragma("unroll")                                                      \
        for (int p = 0; p < 2; ++p) {                                          \
            int ci = p * 256 + tid;                                            \
            int row = ci >> 3;                                                 \
            int c = (ci & 7) ^ (row & 7);                                      \
            lds_dma16(kp + (size_t)((kt0) + row) * HD + c * 8, kd + ci * 8);   \
            lds_dma16(vp + (size_t)row * TSEQ + (kt0) + c * 8, vd + ci * 8);   \
        }                                                                      \
    }

    STAGE_KV(0, 0);
    // phase 1: kt = 0..qtA — both tiles, shared K/V frags, interleaved ILP
    for (int kt = 0; kt <= qtA; ++kt) {
        const int cur = kt & 1;
        __syncthreads();
        STAGE_KV((kt + 1) * 64, cur ^ 1);     // kt+1 <= qtA+1 <= qtB: valid
        attn_tile2(qA0, qA1, qB0, qB1, mA, lA, oA, mB, lB, oB,
                   Ks[cur], Vs[cur], (kt == qtA), l15, quad, relq);
    }
    // phase 2: kt = qtA+1..qtB — B only
    for (int kt = qtA + 1; kt <= qtB; ++kt) {
        const int cur = kt & 1;
        __syncthreads();
        if (kt < qtB) STAGE_KV((kt + 1) * 64, cur ^ 1);
        attn_tile(qB0, qB1, mB, lB, oB, Ks[cur], Vs[cur], (kt == qtB), l15, quad, relq);
    }
#undef STAGE_KV

    const float invA = 1.f / lA, invB = 1.f / lB;
    const size_t baseA = ((size_t)(b * TSEQ + q0A + relq)) * CEMB + h * HD + quad * 4;
    const size_t baseB = ((size_t)(b * TSEQ + q0B + relq)) * CEMB + h * HD + quad * 4;
#pragma unroll
    for (int mt = 0; mt < 4; ++mt) {
        half4 ha = { (_Float16)(oA[mt][0] * invA), (_Float16)(oA[mt][1] * invA),
                     (_Float16)(oA[mt][2] * invA), (_Float16)(oA[mt][3] * invA) };
        half4 hb = { (_Float16)(oB[mt][0] * invB), (_Float16)(oB[mt][1] * invB),
                     (_Float16)(oB[mt][2] * invB), (_Float16)(oB[mt][3] * invB) };
        *(half4*)(o16 + baseA + mt * 16) = ha;
        *(half4*)(o16 + baseB + mt * 16) = hb;
    }
}

// ---------------------------------------------------------------------------
// Kernel 3: y = attn16 @ Wp16^T + b_proj, fp32 out. 64x128 tile -> 1024
// blocks (4/CU) for latency hiding. Same dbuf DMA structure.
// ---------------------------------------------------------------------------
__global__ __launch_bounds__(256)
void proj_gemm(const _Float16* __restrict__ A, const _Float16* __restrict__ B,
               const float* __restrict__ bias, float* __restrict__ out)
{
    __shared__ __align__(16) _Float16 As2[2][64 * 32];
    __shared__ __align__(16) _Float16 Bs2[2][128 * 32];
    const int tid = threadIdx.x, lane = tid & 63, wave = tid >> 6;
    const int wm = wave & 1, wn = wave >> 1;
    const int m0 = blockIdx.y * 64, n0 = blockIdx.x * 128;
    const int l15 = lane & 15, quad = lane >> 4;

    floatx4 acc[2][4];
#pragma unroll
    for (int i = 0; i < 2; ++i)
#pragma unroll
        for (int j = 0; j < 4; ++j) acc[i][j] = (floatx4){0.f, 0.f, 0.f, 0.f};

#define STAGE_A(kk, buf)                                                       \
    {                                                                          \
        int row = tid >> 2, c = (tid & 3) ^ (row & 3);                         \
        lds_dma16(A + (size_t)(m0 + row) * CEMB + (kk) + c * 8,                \
                  As2[buf] + tid * 8);                                         \
    }

    STAGE_A(0, 0);
    stage32(B, Bs2[0], n0, 0, tid);
    for (int kt = 0; kt < 32; ++kt) {
        const int cur = kt & 1;
        __syncthreads();
        if (kt < 31) {
            STAGE_A((kt + 1) * 32, cur ^ 1);
            stage32(B, Bs2[cur ^ 1], n0, (kt + 1) * 32, tid);
        }
        half8 af[2], bf[4];
#pragma unroll
        for (int mt = 0; mt < 2; ++mt) {
            int row = wm * 32 + mt * 16 + l15;
            af[mt] = *(const half8*)(As2[cur] + row * 32 + (quad ^ (row & 3)) * 8);
        }
#pragma unroll
        for (int nt = 0; nt < 4; ++nt) {
            int row = wn * 64 + nt * 16 + l15;
            bf[nt] = *(const half8*)(Bs2[cur] + row * 32 + (quad ^ (row & 3)) * 8);
        }
#pragma unroll
        for (int mt = 0; mt < 2; ++mt)
#pragma unroll
            for (int nt = 0; nt < 4; ++nt)
                acc[mt][nt] = __builtin_amdgcn_mfma_f32_16x16x32_f16(af[mt], bf[nt], acc[mt][nt], 0, 0, 0);
    }
#undef STAGE_A

    const int rbase = quad << 2;
#pragma unroll
    for (int mt = 0; mt < 2; ++mt)
#pragma unroll
        for (int nt = 0; nt < 4; ++nt) {
            int gn = n0 + wn * 64 + nt * 16 + l15;
            float bb = bias[gn];
#pragma unroll
            for (int r = 0; r < 4; ++r) {
                int gm = m0 + wm * 32 + mt * 16 + rbase + r;
                out[(size_t)gm * CEMB + gn] = acc[mt][nt][r] + bb;
            }
        }
}

// ---------------------------------------------------------------------------
extern "C" void kernel_launch(void* const* d_in, const int* in_sizes, int n_in,
                              void* d_out, int out_size, void* d_ws, size_t ws_size,
                              hipStream_t stream) {
    const float* x     = (const float*)d_in[0];
    const float* Wattn = (const float*)d_in[1];
    const float* Wproj = (const float*)d_in[2];
    const float* bproj = (const float*)d_in[3];
    float* out = (float*)d_out;

    const size_t nx  = (size_t)BATCH * TSEQ * CEMB;
    const size_t nwa = (size_t)3 * CEMB * CEMB;
    const size_t nwp = (size_t)CEMB * CEMB;
    const size_t per = (size_t)BATCH * NHEAD * TSEQ * HD;

    _Float16* x16    = (_Float16*)d_ws;
    _Float16* wa16   = x16 + nx;
    _Float16* wp16   = wa16 + nwa;
    _Float16* q16    = wp16 + nwp;
    _Float16* k16    = q16 + per;
    _Float16* v16    = k16 + per;
    _Float16* attn16 = x16;   // alias: x16 fully consumed before attn writes

    const int nconv = (int)((nx + nwa + nwp) / 4);
    cvt_fp16<<<nconv / 256, 256, 0, stream>>>(x, Wattn, Wproj, x16, wa16, wp16);
    qkv_gemm<<<dim3(3 * CEMB / 128, MROWS / 128), 256, 0, stream>>>(x16, wa16, q16, k16, v16);
    attn_fwd<<<dim3(16, BATCH * NHEAD), 256, 0, stream>>>(q16, k16, v16, attn16);
    proj_gemm<<<dim3(CEMB / 128, MROWS / 64), 256, 0, stream>>>(attn16, wp16, bproj, out);
}